// Round 1
// baseline (219.573 us; speedup 1.0000x reference)
//
#include <hip/hip_runtime.h>
#include <hip/hip_bf16.h>

typedef unsigned short u16;
typedef u16 u16x8 __attribute__((ext_vector_type(8)));
typedef __bf16 bf16x8 __attribute__((ext_vector_type(8)));
typedef float f32x4 __attribute__((ext_vector_type(4)));

__device__ __forceinline__ u16 f2bf(float f) {
  union { float f; unsigned u; } v; v.f = f;
  unsigned r = v.u + 0x7fffu + ((v.u >> 16) & 1u);
  return (u16)(r >> 16);
}

__device__ __forceinline__ void gload16(const void* g, void* l) {
  __builtin_amdgcn_global_load_lds((const __attribute__((address_space(1))) void*)g,
                                   (__attribute__((address_space(3))) void*)l, 16, 0, 0);
}

// ---------------- f32 -> bf16 elementwise ----------------
__global__ __launch_bounds__(256) void cvt_bf16(const float* __restrict__ in,
                                                u16* __restrict__ out, int n) {
  int i = (blockIdx.x * 256 + threadIdx.x) * 8;
  if (i >= n) return;
  f32x4 a = *(const f32x4*)(in + i);
  f32x4 b = *(const f32x4*)(in + i + 4);
  u16x8 r;
  r[0] = f2bf(a[0]); r[1] = f2bf(a[1]); r[2] = f2bf(a[2]); r[3] = f2bf(a[3]);
  r[4] = f2bf(b[0]); r[5] = f2bf(b[1]); r[6] = f2bf(b[2]); r[7] = f2bf(b[3]);
  *(u16x8*)(out + i) = r;
}

// ------------- transpose+convert: in [K][N] f32 -> out [N][K] bf16 -------------
__global__ __launch_bounds__(256) void transpose_cvt(const float* __restrict__ in,
                                                     u16* __restrict__ out,
                                                     int K, int N) {
  __shared__ float tile[32][33];
  int n0 = blockIdx.x * 32, k0 = blockIdx.y * 32;
  int tx = threadIdx.x & 31, ty = threadIdx.x >> 5;
  for (int i = 0; i < 32; i += 8)
    tile[ty + i][tx] = in[(long)(k0 + ty + i) * N + n0 + tx];
  __syncthreads();
  for (int i = 0; i < 32; i += 8)
    out[(long)(n0 + ty + i) * K + k0 + tx] = f2bf(tile[tx][ty + i]);
}

// ------------- GEMM: C[M][N] = A[M][K] * Bt[N][K]^T (+bias) -------------
// 128x128 tile, BK=32, 4 waves (2x2), 16x16x32 bf16 MFMA, global_load_lds
// staging with chunk-XOR swizzle (pre-swizzled global source, linear LDS dest).
template<bool F32OUT>
__global__ __launch_bounds__(256) void gemm_bt(
    const u16* __restrict__ A, const u16* __restrict__ Bt,
    void* __restrict__ Cp, const float* __restrict__ bias,
    int M, int N, int K)
{
  __shared__ char lds[2 * 128 * 64];
  char* As = lds;
  char* Bs = lds + 128 * 64;
  const int tid = threadIdx.x;
  const int l = tid & 63, w = tid >> 6;
  const int wr = w >> 1, wc = w & 1;
  const int lr = l & 15, q4 = l >> 4;
  const long row0 = (long)blockIdx.x * 128;
  const long col0 = (long)blockIdx.y * 128;

  f32x4 acc[4][4] = {};

  // staging: LDS chunk (r, c) holds global chunk (c ^ (r&3)); rows are 64B (4 chunks)
  int o0 = w * 2048 + l * 16;
  int o1 = o0 + 1024;
  int r0s = o0 >> 6, c0s = ((o0 >> 4) & 3) ^ (r0s & 3);
  int r1s = o1 >> 6, c1s = ((o1 >> 4) & 3) ^ (r1s & 3);
  const u16* gA0 = A + (row0 + r0s) * K + c0s * 8;
  const u16* gA1 = A + (row0 + r1s) * K + c1s * 8;
  const u16* gB0 = Bt + (col0 + r0s) * K + c0s * 8;
  const u16* gB1 = Bt + (col0 + r1s) * K + c1s * 8;

  for (int k0 = 0; k0 < K; k0 += 32) {
    __syncthreads();
    gload16(gA0 + k0, As + o0);
    gload16(gA1 + k0, As + o1);
    gload16(gB0 + k0, Bs + o0);
    gload16(gB1 + k0, Bs + o1);
    __syncthreads();
    bf16x8 a[4], b[4];
    for (int m = 0; m < 4; ++m) {
      int r = wr * 64 + m * 16 + lr;
      a[m] = *(const bf16x8*)(As + r * 64 + ((q4 ^ (r & 3)) << 4));
    }
    for (int n = 0; n < 4; ++n) {
      int r = wc * 64 + n * 16 + lr;
      b[n] = *(const bf16x8*)(Bs + r * 64 + ((q4 ^ (r & 3)) << 4));
    }
    for (int m = 0; m < 4; ++m)
      for (int n = 0; n < 4; ++n)
        acc[m][n] = __builtin_amdgcn_mfma_f32_16x16x32_bf16(a[m], b[n], acc[m][n], 0, 0, 0);
  }

  for (int n = 0; n < 4; ++n) {
    int col = (int)col0 + wc * 64 + n * 16 + lr;
    float bv = 0.f;
    if (F32OUT) bv = bias[col];
    for (int m = 0; m < 4; ++m) {
      for (int reg = 0; reg < 4; ++reg) {
        long row = row0 + wr * 64 + m * 16 + q4 * 4 + reg;
        float vv = acc[m][n][reg] + bv;
        if (F32OUT) ((float*)Cp)[row * N + col] = vv;
        else        ((u16*)Cp)[row * N + col] = f2bf(vv);
      }
    }
  }
}

// ------------- causal flash attention -------------
// qkv [B*T][3072] bf16 (q|k|v each 1024, head h at h*64). atty [B*T][1024] bf16.
// Block: (qb, h, b); 4 waves x 16 q-rows = 64-row q tile; KV tiles of 64.
#define FXOR(d) (((((d) & 7) ^ (((d) >> 3) & 7))) << 4)

__global__ __launch_bounds__(256) void attn_fwd(
    const u16* __restrict__ qkv, u16* __restrict__ atty)
{
  __shared__ char qs[64 * 128];
  __shared__ char ks[64 * 128];
  __shared__ char vt[64 * 128];         // Vt[d][key], XOR-swizzled
  __shared__ char ps[4][16 * 128];      // per-wave P tile, XOR-swizzled
  const int tid = threadIdx.x;
  const int l = tid & 63, w = tid >> 6;
  const int lr = l & 15, q4 = l >> 4;
  const int qb = blockIdx.x, h = blockIdx.y;
  const int q0 = qb * 64;
  const long base = (long)blockIdx.z * 2048;

  // stage Q tile [64][64] (rows are 128B = 8 chunks; chunk-XOR swizzle)
  {
    int a0 = w * 2048 + l * 16, a1 = a0 + 1024;
    int r0 = a0 >> 7, c0 = ((a0 >> 4) & 7) ^ (r0 & 7);
    int r1 = a1 >> 7, c1 = ((a1 >> 4) & 7) ^ (r1 & 7);
    gload16(qkv + (base + q0 + r0) * 3072 + h * 64 + c0 * 8, qs + a0);
    gload16(qkv + (base + q0 + r1) * 3072 + h * 64 + c1 * 8, qs + a1);
  }
  __syncthreads();
  bf16x8 qf[2];
  for (int kk = 0; kk < 2; ++kk) {
    int r = w * 16 + lr;
    int c = (kk * 4 + q4) ^ (r & 7);
    qf[kk] = *(const bf16x8*)(qs + r * 128 + (c << 4));
  }

  float mrun[4], lsum[4];
  f32x4 o[4] = {};
  for (int i = 0; i < 4; ++i) { mrun[i] = -__builtin_inff(); lsum[i] = 0.f; }

  // K staging addresses
  int a0 = w * 2048 + l * 16, a1 = a0 + 1024;
  int r0 = a0 >> 7, c0 = ((a0 >> 4) & 7) ^ (r0 & 7);
  int r1 = a1 >> 7, c1 = ((a1 >> 4) & 7) ^ (r1 & 7);

  const int nkv = qb + 1;
  for (int t = 0; t < nkv; ++t) {
    const int k0 = t * 64;
    __syncthreads();
    gload16(qkv + (base + k0 + r0) * 3072 + 1024 + h * 64 + c0 * 8, ks + a0);
    gload16(qkv + (base + k0 + r1) * 3072 + 1024 + h * 64 + c1 * 8, ks + a1);
    // V transpose-scatter into vt (coalesced 16B global loads, XOR-spread b16 writes)
    for (int it = 0; it < 2; ++it) {
      int id = it * 256 + tid;
      int key = id >> 3, d0 = (id & 7) << 3;
      u16x8 val = *(const u16x8*)(qkv + (base + k0 + key) * 3072 + 2048 + h * 64 + d0);
      for (int j = 0; j < 8; ++j) {
        int d = d0 + j;
        *(u16*)(vt + d * 128 + ((key * 2) ^ FXOR(d))) = val[j];
      }
    }
    __syncthreads();

    // S = Q K^T  (rows: wave's 16 q-rows; cols: 64 keys)
    f32x4 s[4] = {};
    for (int kk = 0; kk < 2; ++kk) {
      for (int n = 0; n < 4; ++n) {
        int r = n * 16 + lr;
        int c = (kk * 4 + q4) ^ (r & 7);
        bf16x8 kf = *(const bf16x8*)(ks + r * 128 + (c << 4));
        s[n] = __builtin_amdgcn_mfma_f32_16x16x32_bf16(qf[kk], kf, s[n], 0, 0, 0);
      }
    }
    // scale + causal mask (only diagonal tile)
    for (int n = 0; n < 4; ++n)
      for (int reg = 0; reg < 4; ++reg) {
        float v = s[n][reg] * 0.125f;
        if (k0 == q0 && (k0 + n * 16 + lr) > (q0 + w * 16 + q4 * 4 + reg))
          v = -__builtin_inff();
        s[n][reg] = v;
      }
    // online softmax (row r lives in 16-lane quarter; reduce over lanes)
    float pmax[4];
    for (int reg = 0; reg < 4; ++reg) {
      float v = fmaxf(fmaxf(s[0][reg], s[1][reg]), fmaxf(s[2][reg], s[3][reg]));
      for (int off = 1; off < 16; off <<= 1) v = fmaxf(v, __shfl_xor(v, off));
      pmax[reg] = v;
    }
    float scl[4];
    for (int reg = 0; reg < 4; ++reg) {
      float mn = fmaxf(mrun[reg], pmax[reg]);
      scl[reg] = __expf(mrun[reg] - mn);
      mrun[reg] = mn;
      lsum[reg] *= scl[reg];
    }
    for (int n = 0; n < 4; ++n)
      for (int reg = 0; reg < 4; ++reg) o[n][reg] *= scl[reg];
    float psum[4] = {0.f, 0.f, 0.f, 0.f};
    for (int n = 0; n < 4; ++n)
      for (int reg = 0; reg < 4; ++reg) {
        float p = __expf(s[n][reg] - mrun[reg]);
        psum[reg] += p;
        int r = q4 * 4 + reg;
        *(u16*)(ps[w] + r * 128 + (((n * 16 + lr) * 2) ^ ((r & 7) << 4))) = f2bf(p);
      }
    for (int reg = 0; reg < 4; ++reg) {
      float v = psum[reg];
      for (int off = 1; off < 16; off <<= 1) v += __shfl_xor(v, off);
      lsum[reg] += v;
    }
    // O += P V  (A = P from wave-private LDS, B = V^T from vt)
    for (int kk = 0; kk < 2; ++kk) {
      int r = lr;
      bf16x8 pf = *(const bf16x8*)(ps[w] + r * 128 + (((kk * 4 + q4) << 4) ^ ((r & 7) << 4)));
      for (int n = 0; n < 4; ++n) {
        int dd = n * 16 + lr;
        int kb = (kk * 32 + q4 * 8) * 2;
        bf16x8 vf = *(const bf16x8*)(vt + dd * 128 + (kb ^ FXOR(dd)));
        o[n] = __builtin_amdgcn_mfma_f32_16x16x32_bf16(pf, vf, o[n], 0, 0, 0);
      }
    }
  }
  // epilogue: normalize and store
  for (int n = 0; n < 4; ++n)
    for (int reg = 0; reg < 4; ++reg) {
      long row = base + q0 + w * 16 + q4 * 4 + reg;
      atty[row * 1024 + h * 64 + n * 16 + lr] = f2bf(o[n][reg] / lsum[reg]);
    }
}

extern "C" void kernel_launch(void* const* d_in, const int* in_sizes, int n_in,
                              void* d_out, int out_size, void* d_ws, size_t ws_size,
                              hipStream_t stream) {
  const float* x     = (const float*)d_in[0];
  const float* Wqkv  = (const float*)d_in[1];
  const float* Wproj = (const float*)d_in[2];
  const float* bproj = (const float*)d_in[3];
  char* ws = (char*)d_ws;
  u16* xb   = (u16*)(ws);                    // 4096*1024 bf16      (8 MB)
  u16* wqT  = (u16*)(ws + 8388608);          // [3072][1024] bf16   (6 MB)
  u16* wpT  = (u16*)(ws + 14680064);         // [1024][1024] bf16   (2 MB)
  u16* qkv  = (u16*)(ws + 16777216);         // [4096][3072] bf16   (24 MB)
  u16* atty = (u16*)(ws + 41943040);         // [4096][1024] bf16   (8 MB)

  cvt_bf16<<<2048, 256, 0, stream>>>(x, xb, 4194304);
  transpose_cvt<<<dim3(96, 32), 256, 0, stream>>>(Wqkv, wqT, 1024, 3072);
  transpose_cvt<<<dim3(32, 32), 256, 0, stream>>>(Wproj, wpT, 1024, 1024);
  gemm_bt<false><<<dim3(32, 24), 256, 0, stream>>>(xb, wqT, (void*)qkv, nullptr, 4096, 3072, 1024);
  attn_fwd<<<dim3(32, 16, 2), 256, 0, stream>>>(qkv, atty);
  gemm_bt<true><<<dim3(32, 8), 256, 0, stream>>>(atty, wpT, d_out, bproj, 4096, 1024, 1024);
}

// Round 3
// 149.921 us; speedup vs baseline: 1.4646x; 1.4646x over previous
//
#include <hip/hip_runtime.h>
#include <hip/hip_bf16.h>

typedef unsigned short u16;
typedef u16 u16x8 __attribute__((ext_vector_type(8)));
typedef __bf16 bf16x8 __attribute__((ext_vector_type(8)));
typedef float f32x4 __attribute__((ext_vector_type(4)));

__device__ __forceinline__ u16 f2bf(float f) {
  union { float f; unsigned u; } v; v.f = f;
  unsigned r = v.u + 0x7fffu + ((v.u >> 16) & 1u);
  return (u16)(r >> 16);
}

__device__ __forceinline__ float fexp2(float x) {
#if __has_builtin(__builtin_amdgcn_exp2f)
  return __builtin_amdgcn_exp2f(x);
#else
  return exp2f(x);
#endif
}

__device__ __forceinline__ void gload16(const void* g, void* l) {
  __builtin_amdgcn_global_load_lds((const __attribute__((address_space(1))) void*)g,
                                   (__attribute__((address_space(3))) void*)l, 16, 0, 0);
}

// ---------------- f32 -> bf16 elementwise ----------------
__global__ __launch_bounds__(256) void cvt_bf16(const float* __restrict__ in,
                                                u16* __restrict__ out, int n) {
  int i = (blockIdx.x * 256 + threadIdx.x) * 8;
  if (i >= n) return;
  f32x4 a = *(const f32x4*)(in + i);
  f32x4 b = *(const f32x4*)(in + i + 4);
  u16x8 r;
  r[0] = f2bf(a[0]); r[1] = f2bf(a[1]); r[2] = f2bf(a[2]); r[3] = f2bf(a[3]);
  r[4] = f2bf(b[0]); r[5] = f2bf(b[1]); r[6] = f2bf(b[2]); r[7] = f2bf(b[3]);
  *(u16x8*)(out + i) = r;
}

// ------------- transpose+convert: in [K][N] f32 -> out [N][K] bf16 -------------
__global__ __launch_bounds__(256) void transpose_cvt(const float* __restrict__ in,
                                                     u16* __restrict__ out,
                                                     int K, int N) {
  __shared__ float tile[32][33];
  int n0 = blockIdx.x * 32, k0 = blockIdx.y * 32;
  int tx = threadIdx.x & 31, ty = threadIdx.x >> 5;
  for (int i = 0; i < 32; i += 8)
    tile[ty + i][tx] = in[(long)(k0 + ty + i) * N + n0 + tx];
  __syncthreads();
  for (int i = 0; i < 32; i += 8)
    out[(long)(n0 + ty + i) * K + k0 + tx] = f2bf(tile[tx][ty + i]);
}

// ------------- GEMM: C[M][N] = A[M][K] * Bt[N][K]^T (+bias) -------------
template<bool F32OUT>
__global__ __launch_bounds__(256) void gemm_bt(
    const u16* __restrict__ A, const u16* __restrict__ Bt,
    void* __restrict__ Cp, const float* __restrict__ bias,
    int M, int N, int K)
{
  __shared__ char lds[2 * 128 * 64];
  char* As = lds;
  char* Bs = lds + 128 * 64;
  const int tid = threadIdx.x;
  const int l = tid & 63, w = tid >> 6;
  const int wr = w >> 1, wc = w & 1;
  const int lr = l & 15, q4 = l >> 4;
  const long row0 = (long)blockIdx.x * 128;
  const long col0 = (long)blockIdx.y * 128;

  f32x4 acc[4][4] = {};

  int o0 = w * 2048 + l * 16;
  int o1 = o0 + 1024;
  int r0s = o0 >> 6, c0s = ((o0 >> 4) & 3) ^ (r0s & 3);
  int r1s = o1 >> 6, c1s = ((o1 >> 4) & 3) ^ (r1s & 3);
  const u16* gA0 = A + (row0 + r0s) * K + c0s * 8;
  const u16* gA1 = A + (row0 + r1s) * K + c1s * 8;
  const u16* gB0 = Bt + (col0 + r0s) * K + c0s * 8;
  const u16* gB1 = Bt + (col0 + r1s) * K + c1s * 8;

  for (int k0 = 0; k0 < K; k0 += 32) {
    __syncthreads();
    gload16(gA0 + k0, As + o0);
    gload16(gA1 + k0, As + o1);
    gload16(gB0 + k0, Bs + o0);
    gload16(gB1 + k0, Bs + o1);
    __syncthreads();
    bf16x8 a[4], b[4];
    for (int m = 0; m < 4; ++m) {
      int r = wr * 64 + m * 16 + lr;
      a[m] = *(const bf16x8*)(As + r * 64 + ((q4 ^ (r & 3)) << 4));
    }
    for (int n = 0; n < 4; ++n) {
      int r = wc * 64 + n * 16 + lr;
      b[n] = *(const bf16x8*)(Bs + r * 64 + ((q4 ^ (r & 3)) << 4));
    }
    for (int m = 0; m < 4; ++m)
      for (int n = 0; n < 4; ++n)
        acc[m][n] = __builtin_amdgcn_mfma_f32_16x16x32_bf16(a[m], b[n], acc[m][n], 0, 0, 0);
  }

  for (int n = 0; n < 4; ++n) {
    int col = (int)col0 + wc * 64 + n * 16 + lr;
    float bv = 0.f;
    if (F32OUT) bv = bias[col];
    for (int m = 0; m < 4; ++m) {
      for (int reg = 0; reg < 4; ++reg) {
        long row = row0 + wr * 64 + m * 16 + q4 * 4 + reg;
        float vv = acc[m][n][reg] + bv;
        if (F32OUT) ((float*)Cp)[row * N + col] = vv;
        else        ((u16*)Cp)[row * N + col] = f2bf(vv);
      }
    }
  }
}

// ------------- causal flash attention -------------
// qkv [B*T][3072] bf16. atty [B*T][1024] bf16.
// Block: 128 q-rows (8 waves x 16 rows), KV tiles of 64. 512 blocks, all
// co-resident. qb flipped by batch so CU pairs {qb, 15-qb} balance the
// causal triangle exactly.
#define FXOR(d) (((((d) & 7) ^ (((d) >> 3) & 7))) << 4)

__global__ __launch_bounds__(512) void attn_fwd(
    const u16* __restrict__ qkv, u16* __restrict__ atty)
{
  __shared__ char ks[64 * 128];
  __shared__ char vt[64 * 128];         // Vt[d][key], XOR-swizzled
  __shared__ char ps[8][16 * 128];      // per-wave P tile, XOR-swizzled
  const int tid = threadIdx.x;
  const int l = tid & 63, w = tid >> 6;
  const int lr = l & 15, q4 = l >> 4;
  const int h = blockIdx.y;
  const int qb = blockIdx.z ? (15 - (int)blockIdx.x) : (int)blockIdx.x;
  const int q0 = qb * 128;
  const long base = (long)blockIdx.z * 2048;
  const int wrow = q0 + w * 16;
  const int wmax = wrow + 15;

  // Q fragments straight from global, pre-scaled by 0.125*log2(e)
  bf16x8 qf[2];
  for (int kk = 0; kk < 2; ++kk) {
    u16x8 raw = *(const u16x8*)(qkv + (base + wrow + lr) * 3072 + h * 64 + kk * 32 + q4 * 8);
    u16x8 sc;
    for (int j = 0; j < 8; ++j) {
      union { unsigned u; float f; } c; c.u = ((unsigned)raw[j]) << 16;
      sc[j] = f2bf(c.f * 0.18033688f);   // 0.125 * log2(e)
    }
    qf[kk] = *(bf16x8*)&sc;
  }

  float mrun[4], lsum[4];
  f32x4 o[4] = {};
  for (int i = 0; i < 4; ++i) { mrun[i] = -__builtin_inff(); lsum[i] = 0.f; }

  // K staging: one 16B global_load_lds per thread per tile
  const int r0 = tid >> 3;
  const int c0 = (tid & 7) ^ (r0 & 7);
  // V scatter: one 16B load per thread
  const int vkey = tid >> 3, vd0 = (tid & 7) << 3;

  const int nkv = 2 * qb + 2;
  for (int t = 0; t < nkv; ++t) {
    const int k0 = t * 64;
    __syncthreads();
    gload16(qkv + (base + k0 + r0) * 3072 + 1024 + h * 64 + c0 * 8, ks + tid * 16);
    {
      u16x8 val = *(const u16x8*)(qkv + (base + k0 + vkey) * 3072 + 2048 + h * 64 + vd0);
      for (int j = 0; j < 8; ++j) {
        int d = vd0 + j;
        *(u16*)(vt + d * 128 + ((vkey * 2) ^ FXOR(d))) = val[j];
      }
    }
    __syncthreads();
    if (k0 > wmax) continue;            // fully-masked tile for this wave

    // S = Q K^T (scores already in 2^x domain)
    f32x4 s[4] = {};
    for (int kk = 0; kk < 2; ++kk)
      for (int n = 0; n < 4; ++n) {
        int r = n * 16 + lr;
        int c = (kk * 4 + q4) ^ (r & 7);
        bf16x8 kf = *(const bf16x8*)(ks + r * 128 + (c << 4));
        s[n] = __builtin_amdgcn_mfma_f32_16x16x32_bf16(qf[kk], kf, s[n], 0, 0, 0);
      }
    // causal mask: any tile whose max key exceeds the wave's MIN row
    // (round-1 bug: gating on wmax let waves 3,7 attend future keys)
    if (k0 + 63 > wrow) {
      for (int n = 0; n < 4; ++n)
        for (int reg = 0; reg < 4; ++reg)
          if (k0 + n * 16 + lr > wrow + q4 * 4 + reg)
            s[n][reg] = -__builtin_inff();
    }
    // per-row max (rows live on 16-lane groups)
    float pm[4];
    for (int reg = 0; reg < 4; ++reg) {
      float v = fmaxf(fmaxf(s[0][reg], s[1][reg]), fmaxf(s[2][reg], s[3][reg]));
      for (int off = 1; off < 16; off <<= 1) v = fmaxf(v, __shfl_xor(v, off));
      pm[reg] = v;
    }
    // defer-max: rescale only when a row's max grew past threshold
    bool need = (pm[0] > mrun[0] + 8.f) || (pm[1] > mrun[1] + 8.f) ||
                (pm[2] > mrun[2] + 8.f) || (pm[3] > mrun[3] + 8.f);
    if (__any(need)) {
      float scl[4];
      for (int reg = 0; reg < 4; ++reg) {
        float mn = fmaxf(mrun[reg], pm[reg]);
        scl[reg] = fexp2(mrun[reg] - mn);
        mrun[reg] = mn;
        lsum[reg] *= scl[reg];
      }
      for (int n = 0; n < 4; ++n)
        for (int reg = 0; reg < 4; ++reg) o[n][reg] *= scl[reg];
    }
    float psum[4] = {0.f, 0.f, 0.f, 0.f};
    for (int n = 0; n < 4; ++n)
      for (int reg = 0; reg < 4; ++reg) {
        float p = fexp2(s[n][reg] - mrun[reg]);
        psum[reg] += p;
        int r = q4 * 4 + reg;
        *(u16*)(ps[w] + r * 128 + (((n * 16 + lr) * 2) ^ ((r & 7) << 4))) = f2bf(p);
      }
    for (int reg = 0; reg < 4; ++reg) {
      float v = psum[reg];
      for (int off = 1; off < 16; off <<= 1) v += __shfl_xor(v, off);
      lsum[reg] += v;
    }
    // O += P V
    for (int kk = 0; kk < 2; ++kk) {
      bf16x8 pf = *(const bf16x8*)(ps[w] + lr * 128 + (((kk * 4 + q4) << 4) ^ ((lr & 7) << 4)));
      for (int n = 0; n < 4; ++n) {
        int dd = n * 16 + lr;
        bf16x8 vf = *(const bf16x8*)(vt + dd * 128 + ((kk * 64 + q4 * 16) ^ FXOR(dd)));
        o[n] = __builtin_amdgcn_mfma_f32_16x16x32_bf16(pf, vf, o[n], 0, 0, 0);
      }
    }
  }
  // epilogue: normalize and store
  for (int n = 0; n < 4; ++n)
    for (int reg = 0; reg < 4; ++reg) {
      long row = base + q0 + w * 16 + q4 * 4 + reg;
      atty[row * 1024 + h * 64 + n * 16 + lr] = f2bf(o[n][reg] / lsum[reg]);
    }
}

extern "C" void kernel_launch(void* const* d_in, const int* in_sizes, int n_in,
                              void* d_out, int out_size, void* d_ws, size_t ws_size,
                              hipStream_t stream) {
  const float* x     = (const float*)d_in[0];
  const float* Wqkv  = (const float*)d_in[1];
  const float* Wproj = (const float*)d_in[2];
  const float* bproj = (const float*)d_in[3];
  char* ws = (char*)d_ws;
  u16* xb   = (u16*)(ws);                    // 4096*1024 bf16      (8 MB)
  u16* wqT  = (u16*)(ws + 8388608);          // [3072][1024] bf16   (6 MB)
  u16* wpT  = (u16*)(ws + 14680064);         // [1024][1024] bf16   (2 MB)
  u16* qkv  = (u16*)(ws + 16777216);         // [4096][3072] bf16   (24 MB)
  u16* atty = (u16*)(ws + 41943040);         // [4096][1024] bf16   (8 MB)

  cvt_bf16<<<2048, 256, 0, stream>>>(x, xb, 4194304);
  transpose_cvt<<<dim3(96, 32), 256, 0, stream>>>(Wqkv, wqT, 1024, 3072);
  transpose_cvt<<<dim3(32, 32), 256, 0, stream>>>(Wproj, wpT, 1024, 1024);
  gemm_bt<false><<<dim3(32, 24), 256, 0, stream>>>(xb, wqT, (void*)qkv, nullptr, 4096, 3072, 1024);
  attn_fwd<<<dim3(16, 16, 2), 512, 0, stream>>>(qkv, atty);
  gemm_bt<true><<<dim3(32, 8), 256, 0, stream>>>(atty, wpT, d_out, bproj, 4096, 1024, 1024);
}

// Round 4
// 140.732 us; speedup vs baseline: 1.5602x; 1.0653x over previous
//
#include <hip/hip_runtime.h>
#include <hip/hip_bf16.h>

typedef unsigned short u16;
typedef u16 u16x8 __attribute__((ext_vector_type(8)));
typedef __bf16 bf16x8 __attribute__((ext_vector_type(8)));
typedef float f32x4 __attribute__((ext_vector_type(4)));

__device__ __forceinline__ u16 f2bf(float f) {
  union { float f; unsigned u; } v; v.f = f;
  unsigned r = v.u + 0x7fffu + ((v.u >> 16) & 1u);
  return (u16)(r >> 16);
}

// native bf16 convert (compiler emits v_cvt_pk_bf16_f32; RNE)
__device__ __forceinline__ u16 bf(float f) {
  __bf16 h = (__bf16)f;
  union { __bf16 h; u16 u; } c; c.h = h;
  return c.u;
}

__device__ __forceinline__ float fexp2(float x) {
#if __has_builtin(__builtin_amdgcn_exp2f)
  return __builtin_amdgcn_exp2f(x);
#else
  return exp2f(x);
#endif
}

__device__ __forceinline__ float frcp(float x) {
#if __has_builtin(__builtin_amdgcn_rcpf)
  return __builtin_amdgcn_rcpf(x);
#else
  return 1.0f / x;
#endif
}

__device__ __forceinline__ void gload16(const void* g, void* l) {
  __builtin_amdgcn_global_load_lds((const __attribute__((address_space(1))) void*)g,
                                   (__attribute__((address_space(3))) void*)l, 16, 0, 0);
}

// ---------------- f32 -> bf16 elementwise ----------------
__global__ __launch_bounds__(256) void cvt_bf16(const float* __restrict__ in,
                                                u16* __restrict__ out, int n) {
  int i = (blockIdx.x * 256 + threadIdx.x) * 8;
  if (i >= n) return;
  f32x4 a = *(const f32x4*)(in + i);
  f32x4 b = *(const f32x4*)(in + i + 4);
  u16x8 r;
  r[0] = f2bf(a[0]); r[1] = f2bf(a[1]); r[2] = f2bf(a[2]); r[3] = f2bf(a[3]);
  r[4] = f2bf(b[0]); r[5] = f2bf(b[1]); r[6] = f2bf(b[2]); r[7] = f2bf(b[3]);
  *(u16x8*)(out + i) = r;
}

// ------------- transpose+convert: in [K][N] f32 -> out [N][K] bf16 -------------
__global__ __launch_bounds__(256) void transpose_cvt(const float* __restrict__ in,
                                                     u16* __restrict__ out,
                                                     int K, int N) {
  __shared__ float tile[32][33];
  int n0 = blockIdx.x * 32, k0 = blockIdx.y * 32;
  int tx = threadIdx.x & 31, ty = threadIdx.x >> 5;
  for (int i = 0; i < 32; i += 8)
    tile[ty + i][tx] = in[(long)(k0 + ty + i) * N + n0 + tx];
  __syncthreads();
  for (int i = 0; i < 32; i += 8)
    out[(long)(n0 + ty + i) * K + k0 + tx] = f2bf(tile[tx][ty + i]);
}

// ------------- GEMM: C[M][N] = A[M][K] * Bt[N][K]^T (+bias) -------------
// BM x BN tile, BK=32, 4 waves (2x2), 16x16x32 bf16 MFMA.
template<int BM, int BN, bool F32OUT>
__global__ __launch_bounds__(256) void gemm_bt(
    const u16* __restrict__ A, const u16* __restrict__ Bt,
    void* __restrict__ Cp, const float* __restrict__ bias,
    int M, int N, int K)
{
  constexpr int MR = BM / 32, NR = BN / 32;   // per-wave fragment repeats
  constexpr int RA = BM / 64, RB = BN / 64;   // staging rounds
  __shared__ char lds[(BM + BN) * 64];
  char* As = lds;
  char* Bs = lds + BM * 64;
  const int tid = threadIdx.x;
  const int l = tid & 63, w = tid >> 6;
  const int wr = w >> 1, wc = w & 1;
  const int lr = l & 15, q4 = l >> 4;
  const long row0 = (long)blockIdx.x * BM;
  const long col0 = (long)blockIdx.y * BN;

  f32x4 acc[MR][NR] = {};

  const u16* gA[RA];
  int oA[RA];
  for (int i = 0; i < RA; ++i) {
    int o = i * 4096 + tid * 16;
    int r = o >> 6, c = ((o >> 4) & 3) ^ (r & 3);
    oA[i] = o;
    gA[i] = A + (row0 + r) * K + c * 8;
  }
  const u16* gB[RB];
  int oB[RB];
  for (int i = 0; i < RB; ++i) {
    int o = i * 4096 + tid * 16;
    int r = o >> 6, c = ((o >> 4) & 3) ^ (r & 3);
    oB[i] = o;
    gB[i] = Bt + (col0 + r) * K + c * 8;
  }

  for (int k0 = 0; k0 < K; k0 += 32) {
    __syncthreads();
    for (int i = 0; i < RA; ++i) gload16(gA[i] + k0, As + oA[i]);
    for (int i = 0; i < RB; ++i) gload16(gB[i] + k0, Bs + oB[i]);
    __syncthreads();
    bf16x8 a[MR], b[NR];
    for (int m = 0; m < MR; ++m) {
      int r = wr * (BM / 2) + m * 16 + lr;
      a[m] = *(const bf16x8*)(As + r * 64 + ((q4 ^ (r & 3)) << 4));
    }
    for (int n = 0; n < NR; ++n) {
      int r = wc * (BN / 2) + n * 16 + lr;
      b[n] = *(const bf16x8*)(Bs + r * 64 + ((q4 ^ (r & 3)) << 4));
    }
    for (int m = 0; m < MR; ++m)
      for (int n = 0; n < NR; ++n)
        acc[m][n] = __builtin_amdgcn_mfma_f32_16x16x32_bf16(a[m], b[n], acc[m][n], 0, 0, 0);
  }

  for (int n = 0; n < NR; ++n) {
    int col = (int)col0 + wc * (BN / 2) + n * 16 + lr;
    float bv = 0.f;
    if (F32OUT) bv = bias[col];
    for (int m = 0; m < MR; ++m) {
      for (int reg = 0; reg < 4; ++reg) {
        long row = row0 + wr * (BM / 2) + m * 16 + q4 * 4 + reg;
        float vv = acc[m][n][reg] + bv;
        if (F32OUT) ((float*)Cp)[row * N + col] = vv;
        else        ((u16*)Cp)[row * N + col] = f2bf(vv);
      }
    }
  }
}

// ------------- causal flash attention (double-buffered K/V) -------------
// qkv [B*T][3072] bf16. atty [B*T][1024] bf16.
// Block: 128 q-rows (8 waves x 16 rows), KV tiles of 64, K/V double-buffered:
// stage(t+1) issued before compute(t), one barrier per tile.
#define FXOR(d) (((((d) & 7) ^ (((d) >> 3) & 7))) << 4)

__global__ __launch_bounds__(512) void attn_fwd(
    const u16* __restrict__ qkv, u16* __restrict__ atty)
{
  __shared__ char ksmem[2 * 64 * 128];
  __shared__ char vtmem[2 * 64 * 128];  // Vt[d][key], XOR-swizzled
  __shared__ char ps[8][16 * 128];      // per-wave P tile, XOR-swizzled
  const int tid = threadIdx.x;
  const int l = tid & 63, w = tid >> 6;
  const int lr = l & 15, q4 = l >> 4;
  const int h = blockIdx.y;
  const int qb = blockIdx.z ? (15 - (int)blockIdx.x) : (int)blockIdx.x;
  const int q0 = qb * 128;
  const long base = (long)blockIdx.z * 2048;
  const int wrow = q0 + w * 16;
  const int wmax = wrow + 15;

  // Q fragments straight from global, pre-scaled by 0.125*log2(e)
  bf16x8 qf[2];
  for (int kk = 0; kk < 2; ++kk) {
    u16x8 raw = *(const u16x8*)(qkv + (base + wrow + lr) * 3072 + h * 64 + kk * 32 + q4 * 8);
    u16x8 sc;
    for (int j = 0; j < 8; ++j) {
      union { unsigned u; float f; } c; c.u = ((unsigned)raw[j]) << 16;
      sc[j] = bf(c.f * 0.18033688f);   // 0.125 * log2(e)
    }
    qf[kk] = *(bf16x8*)&sc;
  }

  float mrun[4], lsum[4];
  f32x4 o[4] = {};
  for (int i = 0; i < 4; ++i) { mrun[i] = -__builtin_inff(); lsum[i] = 0.f; }

  // K staging: one 16B global_load_lds per thread per tile
  const int r0 = tid >> 3;
  const int c0 = (tid & 7) ^ (r0 & 7);
  const u16* kgp = qkv + (base + r0) * 3072 + 1024 + h * 64 + c0 * 8;
  // V: one 16B global load -> regs -> swizzled scatter
  const int vkey = tid >> 3, vd0 = (tid & 7) << 3;
  const u16* vgp = qkv + (base + vkey) * 3072 + 2048 + h * 64 + vd0;

  const int nkv = 2 * qb + 2;

  // prologue: stage tile 0 into buffer 0
  {
    u16x8 v0 = *(const u16x8*)(vgp);
    gload16(kgp, ksmem + tid * 16);
    for (int j = 0; j < 8; ++j) {
      int d = vd0 + j;
      *(u16*)(vtmem + d * 128 + ((vkey * 2) ^ FXOR(d))) = v0[j];
    }
  }
  __syncthreads();

  for (int t = 0; t < nkv; ++t) {
    const int cur = t & 1;
    const int k0 = t * 64;
    char* ks = ksmem + cur * 8192;
    char* vt = vtmem + cur * 8192;
    const bool more = (t + 1) < nkv;
    u16x8 vn;
    if (more) {
      vn = *(const u16x8*)(vgp + (long)(t + 1) * 64 * 3072);
      gload16(kgp + (long)(t + 1) * 64 * 3072, ksmem + (cur ^ 1) * 8192 + tid * 16);
    }

    if (k0 <= wmax) {
      // S = Q K^T (scores already in 2^x domain)
      f32x4 s[4] = {};
      __builtin_amdgcn_s_setprio(1);
      for (int kk = 0; kk < 2; ++kk)
        for (int n = 0; n < 4; ++n) {
          int r = n * 16 + lr;
          int c = (kk * 4 + q4) ^ (r & 7);
          bf16x8 kf = *(const bf16x8*)(ks + r * 128 + (c << 4));
          s[n] = __builtin_amdgcn_mfma_f32_16x16x32_bf16(qf[kk], kf, s[n], 0, 0, 0);
        }
      __builtin_amdgcn_s_setprio(0);
      // causal mask: any tile whose max key exceeds the wave's MIN row
      if (k0 + 63 > wrow) {
        for (int n = 0; n < 4; ++n)
          for (int reg = 0; reg < 4; ++reg)
            if (k0 + n * 16 + lr > wrow + q4 * 4 + reg)
              s[n][reg] = -__builtin_inff();
      }
      // per-row max (rows live on 16-lane groups)
      float pm[4];
      for (int reg = 0; reg < 4; ++reg) {
        float v = fmaxf(fmaxf(s[0][reg], s[1][reg]), fmaxf(s[2][reg], s[3][reg]));
        for (int off = 1; off < 16; off <<= 1) v = fmaxf(v, __shfl_xor(v, off));
        pm[reg] = v;
      }
      // defer-max: rescale only when a row's max grew past threshold
      bool need = (pm[0] > mrun[0] + 8.f) || (pm[1] > mrun[1] + 8.f) ||
                  (pm[2] > mrun[2] + 8.f) || (pm[3] > mrun[3] + 8.f);
      if (__any(need)) {
        float scl[4];
        for (int reg = 0; reg < 4; ++reg) {
          float mn = fmaxf(mrun[reg], pm[reg]);
          scl[reg] = fexp2(mrun[reg] - mn);
          mrun[reg] = mn;
          lsum[reg] *= scl[reg];
        }
        for (int n = 0; n < 4; ++n)
          for (int reg = 0; reg < 4; ++reg) o[n][reg] *= scl[reg];
      }
      float psum[4] = {0.f, 0.f, 0.f, 0.f};
      for (int n = 0; n < 4; ++n)
        for (int reg = 0; reg < 4; ++reg) {
          float p = fexp2(s[n][reg] - mrun[reg]);
          psum[reg] += p;
          int rr = q4 * 4 + reg;
          int swz = ((rr & 7) << 4) ^ ((rr >> 3) << 5);
          *(u16*)(ps[w] + rr * 128 + (((n * 16 + lr) * 2) ^ swz)) = bf(p);
        }
      for (int reg = 0; reg < 4; ++reg) {
        float v = psum[reg];
        for (int off = 1; off < 16; off <<= 1) v += __shfl_xor(v, off);
        lsum[reg] += v;
      }
      // O += P V
      const int swzr = ((lr & 7) << 4) ^ ((lr >> 3) << 5);
      __builtin_amdgcn_s_setprio(1);
      for (int kk = 0; kk < 2; ++kk) {
        bf16x8 pf = *(const bf16x8*)(ps[w] + lr * 128 + ((kk * 64 + q4 * 16) ^ swzr));
        for (int n = 0; n < 4; ++n) {
          int dd = n * 16 + lr;
          bf16x8 vf = *(const bf16x8*)(vt + dd * 128 + ((kk * 64 + q4 * 16) ^ FXOR(dd)));
          o[n] = __builtin_amdgcn_mfma_f32_16x16x32_bf16(pf, vf, o[n], 0, 0, 0);
        }
      }
      __builtin_amdgcn_s_setprio(0);
    }

    if (more) {
      char* vtn = vtmem + (cur ^ 1) * 8192;
      for (int j = 0; j < 8; ++j) {
        int d = vd0 + j;
        *(u16*)(vtn + d * 128 + ((vkey * 2) ^ FXOR(d))) = vn[j];
      }
      __syncthreads();   // drains K DMA (vmcnt) + publishes V scatter
    }
  }
  // epilogue: normalize and store
  float inv[4];
  for (int reg = 0; reg < 4; ++reg) inv[reg] = frcp(lsum[reg]);
  for (int n = 0; n < 4; ++n)
    for (int reg = 0; reg < 4; ++reg) {
      long row = base + q0 + w * 16 + q4 * 4 + reg;
      atty[row * 1024 + h * 64 + n * 16 + lr] = bf(o[n][reg] * inv[reg]);
    }
}

extern "C" void kernel_launch(void* const* d_in, const int* in_sizes, int n_in,
                              void* d_out, int out_size, void* d_ws, size_t ws_size,
                              hipStream_t stream) {
  const float* x     = (const float*)d_in[0];
  const float* Wqkv  = (const float*)d_in[1];
  const float* Wproj = (const float*)d_in[2];
  const float* bproj = (const float*)d_in[3];
  char* ws = (char*)d_ws;
  u16* xb   = (u16*)(ws);                    // 4096*1024 bf16      (8 MB)
  u16* wqT  = (u16*)(ws + 8388608);          // [3072][1024] bf16   (6 MB)
  u16* wpT  = (u16*)(ws + 14680064);         // [1024][1024] bf16   (2 MB)
  u16* qkv  = (u16*)(ws + 16777216);         // [4096][3072] bf16   (24 MB)
  u16* atty = (u16*)(ws + 41943040);         // [4096][1024] bf16   (8 MB)

  cvt_bf16<<<2048, 256, 0, stream>>>(x, xb, 4194304);
  transpose_cvt<<<dim3(96, 32), 256, 0, stream>>>(Wqkv, wqT, 1024, 3072);
  transpose_cvt<<<dim3(32, 32), 256, 0, stream>>>(Wproj, wpT, 1024, 1024);
  gemm_bt<128, 128, false><<<dim3(32, 24), 256, 0, stream>>>(xb, wqT, (void*)qkv, nullptr, 4096, 3072, 1024);
  attn_fwd<<<dim3(16, 16, 2), 512, 0, stream>>>(qkv, atty);
  gemm_bt<128, 64, true><<<dim3(32, 16), 256, 0, stream>>>(atty, wpT, d_out, bproj, 4096, 1024, 1024);
}